// Round 1
// baseline (383.735 us; speedup 1.0000x reference)
//
#include <hip/hip_runtime.h>

typedef __attribute__((ext_vector_type(8))) short s16x8;
typedef __attribute__((ext_vector_type(4))) float f32x4;

#define AS1 __attribute__((address_space(1)))
#define AS3 __attribute__((address_space(3)))

__device__ __forceinline__ unsigned short f2bf(float f) {
    union { float f; unsigned u; } c; c.f = f;
    return (unsigned short)((c.u + 0x7FFFu + ((c.u >> 16) & 1u)) >> 16);
}

// ---------------- fp32 -> bf16 convert (vectorized) ----------------
__global__ void k_f32_to_bf16(const float* __restrict__ src,
                              unsigned short* __restrict__ dst, int n8) {
    int idx = blockIdx.x * 256 + threadIdx.x;
    int stride = gridDim.x * 256;
    for (int i = idx; i < n8; i += stride) {
        const float4* s = (const float4*)src + (size_t)i * 2;
        float4 a = s[0], b = s[1];
        s16x8 o;
        o[0] = (short)f2bf(a.x); o[1] = (short)f2bf(a.y);
        o[2] = (short)f2bf(a.z); o[3] = (short)f2bf(a.w);
        o[4] = (short)f2bf(b.x); o[5] = (short)f2bf(b.y);
        o[6] = (short)f2bf(b.z); o[7] = (short)f2bf(b.w);
        *((s16x8*)dst + i) = o;
    }
}

// -------- transpose + convert: W[K][N] fp32 -> Wt[N][K] bf16 --------
__global__ __launch_bounds__(256) void k_transpose_bf16(
    const float* __restrict__ W, unsigned short* __restrict__ Wt, int K, int N) {
    __shared__ float t[64][65];
    const int nk = K >> 6;
    const int k0 = (blockIdx.x % nk) << 6;
    const int n0 = (blockIdx.x / nk) << 6;
    const int tid = threadIdx.x;
#pragma unroll
    for (int it = 0; it < 4; it++) {
        int idx = tid + (it << 8);
        int r = idx >> 4, c4 = (idx & 15) << 2;
        float4 v = *(const float4*)(W + (size_t)(k0 + r) * N + n0 + c4);
        t[r][c4] = v.x; t[r][c4 + 1] = v.y; t[r][c4 + 2] = v.z; t[r][c4 + 3] = v.w;
    }
    __syncthreads();
#pragma unroll
    for (int it = 0; it < 2; it++) {
        int idx = tid + (it << 8);
        int rn = idx >> 3, c8 = (idx & 7) << 3;
        s16x8 o;
#pragma unroll
        for (int j = 0; j < 8; j++) o[j] = (short)f2bf(t[c8 + j][rn]);
        *(s16x8*)(Wt + (size_t)(n0 + rn) * K + k0 + c8) = o;
    }
}

// ---------------- GEMM: C[M][N] = A[M][K] * Bt[N][K]^T ----------------
// mode 0: epilogue +bias, +wpe for q/k, scatter bf16 to Q/K/V (B,H,T,hs)
// mode 1: epilogue +bias, write fp32 to Fo
__global__ __launch_bounds__(256, 2) void k_gemm_bt(
    const unsigned short* __restrict__ A, const unsigned short* __restrict__ Bt,
    const float* __restrict__ bias, const float* __restrict__ wpe,
    unsigned short* __restrict__ Qo, unsigned short* __restrict__ Ko,
    unsigned short* __restrict__ Vo, float* __restrict__ Fo,
    int N, int K, int mode) {
    __shared__ unsigned short Alds[8192];   // [128][64] bf16, st-swizzled
    __shared__ unsigned short Blds[8192];
    const int tid = threadIdx.x;
    const int lane = tid & 63, wid = tid >> 6;
    const int ntile = N >> 7;
    const int m0 = (int)(blockIdx.x / ntile) << 7;
    const int n0 = (int)(blockIdx.x % ntile) << 7;
    const int wm = wid & 1, wn = wid >> 1;
    const int lr = lane >> 3, ls = lane & 7;
    const int l15 = lane & 15, lg = lane >> 4;

    const f32x4 vzero = {0.f, 0.f, 0.f, 0.f};
    f32x4 acc[4][4];
#pragma unroll
    for (int i = 0; i < 4; i++)
#pragma unroll
        for (int j = 0; j < 4; j++) acc[i][j] = vzero;

    for (int k0 = 0; k0 < K; k0 += 64) {
        // stage A,B tiles: linear LDS dest, pre-swizzled global source (T2/m201)
#pragma unroll
        for (int i = 0; i < 4; i++) {
            int r = (wid << 5) + (i << 3) + lr;
            int sl = (ls ^ (r & 7)) << 3;
            __builtin_amdgcn_global_load_lds(
                (const AS1 void*)(A + (size_t)(m0 + r) * K + k0 + sl),
                (AS3 void*)(Alds + (wid << 11) + (i << 9)), 16, 0, 0);
            __builtin_amdgcn_global_load_lds(
                (const AS1 void*)(Bt + (size_t)(n0 + r) * K + k0 + sl),
                (AS3 void*)(Blds + (wid << 11) + (i << 9)), 16, 0, 0);
        }
        __syncthreads();
#pragma unroll
        for (int kk = 0; kk < 2; kk++) {
            s16x8 af[4], bfr[4];
#pragma unroll
            for (int mi = 0; mi < 4; mi++) {
                int row = (wm << 6) + (mi << 4) + l15;
                int slot = lg + (kk << 2);
                af[mi] = *(const s16x8*)((const char*)Alds + row * 128 +
                                         ((slot ^ (row & 7)) << 4));
            }
#pragma unroll
            for (int ni = 0; ni < 4; ni++) {
                int row = (wn << 6) + (ni << 4) + l15;
                int slot = lg + (kk << 2);
                bfr[ni] = *(const s16x8*)((const char*)Blds + row * 128 +
                                          ((slot ^ (row & 7)) << 4));
            }
#pragma unroll
            for (int mi = 0; mi < 4; mi++)
#pragma unroll
                for (int ni = 0; ni < 4; ni++)
                    acc[mi][ni] = __builtin_amdgcn_mfma_f32_16x16x32_bf16(
                        af[mi], bfr[ni], acc[mi][ni], 0, 0, 0);
        }
        __syncthreads();
    }

    if (mode == 0) {
#pragma unroll
        for (int ni = 0; ni < 4; ni++) {
            int n = n0 + (wn << 6) + (ni << 4) + l15;
            int which = n >> 10, rem = n & 1023;
            int h = rem >> 6, s = rem & 63;
            unsigned short* out = (which == 0) ? Qo : ((which == 1) ? Ko : Vo);
            float bv = bias[n];
#pragma unroll
            for (int mi = 0; mi < 4; mi++) {
#pragma unroll
                for (int j = 0; j < 4; j++) {
                    int m = m0 + (wm << 6) + (mi << 4) + (lg << 2) + j;
                    int b = m >> 11, t = m & 2047;
                    float v = acc[mi][ni][j] + bv;
                    if (which < 2) v += wpe[((((t << 4) + h) & 2047) << 6) + s];
                    out[(size_t)(b * 16 + h) * 131072 + (size_t)t * 64 + s] = f2bf(v);
                }
            }
        }
    } else {
#pragma unroll
        for (int ni = 0; ni < 4; ni++) {
            int n = n0 + (wn << 6) + (ni << 4) + l15;
            float bv = bias[n];
#pragma unroll
            for (int mi = 0; mi < 4; mi++) {
#pragma unroll
                for (int j = 0; j < 4; j++) {
                    int m = m0 + (wm << 6) + (mi << 4) + (lg << 2) + j;
                    Fo[(size_t)m * N + n] = acc[mi][ni][j] + bv;
                }
            }
        }
    }
}

// ---------------- flash attention (causal), swapped-QK^T ----------------
// grid: (B*H) * 8 q-tiles of 256 rows; 4 waves, wave w owns q rows
// {qt0 + qi*64 + w*16 .. +15} for qi=0..3
__global__ __launch_bounds__(256, 2) void k_attn(
    const unsigned short* __restrict__ Qg, const unsigned short* __restrict__ Kg,
    const unsigned short* __restrict__ Vg, unsigned short* __restrict__ Yg) {
    __shared__ unsigned short Klds[4096];    // [64 kv][64 s], swizzled
    __shared__ unsigned short Vtlds[4096];   // [64 s][64 kv], swizzled
    __shared__ unsigned short Plds[16384];   // per-wave [64 q][64 kv], swizzled
    const int tid = threadIdx.x, lane = tid & 63, wid = tid >> 6;
    const int l15 = lane & 15, lg = lane >> 4;
    const int lr = lane >> 3, ls = lane & 7;
    const int bh = blockIdx.x >> 3, qt = blockIdx.x & 7;
    const int b = bh >> 4, h = bh & 15;
    const size_t base = (size_t)bh * 131072;
    const int qt0 = qt << 8;

    // Q fragments in registers (B-operand of S^T = mfma(K, Q))
    s16x8 qf[4][2];
#pragma unroll
    for (int qi = 0; qi < 4; qi++) {
        int qrow = qt0 + (qi << 6) + (wid << 4) + l15;
#pragma unroll
        for (int kk = 0; kk < 2; kk++)
            qf[qi][kk] = *(const s16x8*)(Qg + base + (size_t)qrow * 64 +
                                         (kk << 5) + (lg << 3));
    }

    const f32x4 vzero = {0.f, 0.f, 0.f, 0.f};
    f32x4 o[4][4];
#pragma unroll
    for (int i = 0; i < 4; i++)
#pragma unroll
        for (int j = 0; j < 4; j++) o[i][j] = vzero;
    float mrun[4], lrun[4];
#pragma unroll
    for (int qi = 0; qi < 4; qi++) { mrun[qi] = -3.0e38f; lrun[qi] = 0.f; }

    const int ntiles = (qt << 2) + 4;
    for (int tI = 0; tI < ntiles; tI++) {
        const int kv0 = tI << 6;
        // stage K (async, pre-swizzled source)
#pragma unroll
        for (int i = 0; i < 2; i++) {
            int r = (wid << 4) + (i << 3) + lr;
            int sl = (ls ^ (r & 7)) << 3;
            __builtin_amdgcn_global_load_lds(
                (const AS1 void*)(Kg + base + (size_t)(kv0 + r) * 64 + sl),
                (AS3 void*)(Klds + (wid << 10) + (i << 9)), 16, 0, 0);
        }
        // stage V transposed (reg path, scalar swizzled writes)
#pragma unroll
        for (int it = 0; it < 2; it++) {
            int idx = tid + (it << 8);
            int kv = idx >> 3, s0 = (idx & 7) << 3;
            s16x8 vv = *(const s16x8*)(Vg + base + (size_t)(kv0 + kv) * 64 + s0);
#pragma unroll
            for (int j = 0; j < 8; j++) {
                int srow = s0 + j;
                *(unsigned short*)((char*)Vtlds + srow * 128 +
                                   (((kv >> 3) ^ (srow & 7)) << 4) +
                                   ((kv & 7) << 1)) = (unsigned short)vv[j];
            }
        }
        __syncthreads();

        // S^T = K * Q^T  (acc: col=q=l15, row=kv=lg*4+j)
        f32x4 sacc[4][4];
#pragma unroll
        for (int i = 0; i < 4; i++)
#pragma unroll
            for (int j = 0; j < 4; j++) sacc[i][j] = vzero;
#pragma unroll
        for (int kk = 0; kk < 2; kk++) {
            s16x8 kf[4];
#pragma unroll
            for (int ki = 0; ki < 4; ki++) {
                int row = (ki << 4) + l15;
                int slot = lg + (kk << 2);
                kf[ki] = *(const s16x8*)((const char*)Klds + row * 128 +
                                         ((slot ^ (row & 7)) << 4));
            }
#pragma unroll
            for (int ki = 0; ki < 4; ki++)
#pragma unroll
                for (int qi = 0; qi < 4; qi++)
                    sacc[ki][qi] = __builtin_amdgcn_mfma_f32_16x16x32_bf16(
                        kf[ki], qf[qi][kk], sacc[ki][qi], 0, 0, 0);
        }

        // online softmax per q-column (in-lane over 16 + 2 shfl_xor)
#pragma unroll
        for (int qi = 0; qi < 4; qi++) {
            const int qcol = qt0 + (qi << 6) + (wid << 4) + l15;
            float tm = -3.0e38f;
#pragma unroll
            for (int ki = 0; ki < 4; ki++) {
#pragma unroll
                for (int j = 0; j < 4; j++) {
                    int kvg = kv0 + (ki << 4) + (lg << 2) + j;
                    float sv = sacc[ki][qi][j] * 0.125f;
                    if (kvg > qcol) sv = -3.0e38f;
                    sacc[ki][qi][j] = sv;
                    tm = fmaxf(tm, sv);
                }
            }
            tm = fmaxf(tm, __shfl_xor(tm, 16, 64));
            tm = fmaxf(tm, __shfl_xor(tm, 32, 64));
            float mnew = fmaxf(mrun[qi], tm);
            float rfac = __expf(mrun[qi] - mnew);
            mrun[qi] = mnew;
            float ps = 0.f;
#pragma unroll
            for (int ki = 0; ki < 4; ki++) {
#pragma unroll
                for (int j = 0; j < 4; j++) {
                    float p = __expf(sacc[ki][qi][j] - mnew);
                    sacc[ki][qi][j] = p;
                    ps += p;
                }
            }
            ps += __shfl_xor(ps, 16, 64);
            ps += __shfl_xor(ps, 32, 64);
            lrun[qi] = lrun[qi] * rfac + ps;
            // rescale O rows (row q = lg*4+j needs column-q's factor)
#pragma unroll
            for (int j = 0; j < 4; j++) {
                float rj = __shfl(rfac, (lane & 48) | ((lg << 2) + j), 64);
#pragma unroll
                for (int si = 0; si < 4; si++) o[qi][si][j] *= rj;
            }
            // pack P -> per-wave LDS (q-row major, swizzled), b64 writes
#pragma unroll
            for (int ki = 0; ki < 4; ki++) {
                unsigned long long pk =
                    (unsigned long long)f2bf(sacc[ki][qi][0]) |
                    ((unsigned long long)f2bf(sacc[ki][qi][1]) << 16) |
                    ((unsigned long long)f2bf(sacc[ki][qi][2]) << 32) |
                    ((unsigned long long)f2bf(sacc[ki][qi][3]) << 48);
                int qlocal = (qi << 4) + l15;
                int kvl = (ki << 4) + (lg << 2);
                int slot = kvl >> 3;
                *(unsigned long long*)((char*)Plds + (wid << 13) + qlocal * 128 +
                                       ((slot ^ (qlocal & 7)) << 4) +
                                       ((kvl & 7) << 1)) = pk;
            }
        }

        // O += P * V
#pragma unroll
        for (int kk = 0; kk < 2; kk++) {
            s16x8 vf[4];
#pragma unroll
            for (int si = 0; si < 4; si++) {
                int row = (si << 4) + l15;
                int slot = lg + (kk << 2);
                vf[si] = *(const s16x8*)((const char*)Vtlds + row * 128 +
                                         ((slot ^ (row & 7)) << 4));
            }
#pragma unroll
            for (int qi = 0; qi < 4; qi++) {
                int row = (qi << 4) + l15;
                int slot = lg + (kk << 2);
                s16x8 pf = *(const s16x8*)((const char*)Plds + (wid << 13) +
                                           row * 128 + ((slot ^ (row & 7)) << 4));
#pragma unroll
                for (int si = 0; si < 4; si++)
                    o[qi][si] = __builtin_amdgcn_mfma_f32_16x16x32_bf16(
                        pf, vf[si], o[qi][si], 0, 0, 0);
            }
        }
        __syncthreads();
    }

    // epilogue: divide by l, write y[b][t][h*64+s] bf16
#pragma unroll
    for (int qi = 0; qi < 4; qi++) {
#pragma unroll
        for (int j = 0; j < 4; j++) {
            float lv = __shfl(lrun[qi], (lane & 48) | ((lg << 2) + j), 64);
            float linv = 1.0f / lv;
            int qg = qt0 + (qi << 6) + (wid << 4) + (lg << 2) + j;
            size_t rowoff = ((size_t)b * 2048 + qg) * 1024 + (h << 6);
#pragma unroll
            for (int si = 0; si < 4; si++) {
                int sg = (si << 4) + l15;
                Yg[rowoff + sg] = f2bf(o[qi][si][j] * linv);
            }
        }
    }
}

extern "C" void kernel_launch(void* const* d_in, const int* in_sizes, int n_in,
                              void* d_out, int out_size, void* d_ws, size_t ws_size,
                              hipStream_t stream) {
    const float* x   = (const float*)d_in[0];
    const float* w1  = (const float*)d_in[1];
    const float* b1  = (const float*)d_in[2];
    const float* w2  = (const float*)d_in[3];
    const float* b2  = (const float*)d_in[4];
    const float* wpe = (const float*)d_in[5];
    float* out = (float*)d_out;

    char* ws = (char*)d_ws;
    unsigned short* xb  = (unsigned short*)(ws);              // 16.78 MB
    unsigned short* w1t = (unsigned short*)(ws + 16777216);   //  6.29 MB
    unsigned short* w2t = (unsigned short*)(ws + 23068672);   //  2.10 MB
    unsigned short* Qb  = (unsigned short*)(ws + 25165824);   // 16.78 MB
    unsigned short* Kb  = (unsigned short*)(ws + 41943040);   // 16.78 MB
    unsigned short* Vb  = (unsigned short*)(ws + 58720256);   // 16.78 MB
    unsigned short* Yb  = (unsigned short*)(ws + 75497472);   // 16.78 MB -> 92.3 MB total

    k_f32_to_bf16<<<2048, 256, 0, stream>>>(x, xb, 8388608 / 8);
    k_transpose_bf16<<<768, 256, 0, stream>>>(w1, w1t, 1024, 3072);
    k_transpose_bf16<<<256, 256, 0, stream>>>(w2, w2t, 1024, 1024);
    k_gemm_bt<<<64 * 24, 256, 0, stream>>>(xb, w1t, b1, wpe, Qb, Kb, Vb,
                                           nullptr, 3072, 1024, 0);
    k_attn<<<512, 256, 0, stream>>>(Qb, Kb, Vb, Yb);
    k_gemm_bt<<<64 * 8, 256, 0, stream>>>(Yb, w2t, b2, nullptr, nullptr, nullptr,
                                          nullptr, out, 1024, 1024, 1);
}

// Round 2
// 312.584 us; speedup vs baseline: 1.2276x; 1.2276x over previous
//
#include <hip/hip_runtime.h>

typedef __attribute__((ext_vector_type(8))) short s16x8;
typedef __attribute__((ext_vector_type(4))) float f32x4;
typedef __attribute__((ext_vector_type(4))) unsigned short u16x4;

#define AS1 __attribute__((address_space(1)))
#define AS3 __attribute__((address_space(3)))

__device__ __forceinline__ unsigned short f2bf(float f) {
    union { float f; unsigned u; } c; c.f = f;
    return (unsigned short)((c.u + 0x7FFFu + ((c.u >> 16) & 1u)) >> 16);
}

// ---------------- fp32 -> bf16 convert (vectorized) ----------------
__global__ void k_f32_to_bf16(const float* __restrict__ src,
                              unsigned short* __restrict__ dst, int n8) {
    int idx = blockIdx.x * 256 + threadIdx.x;
    int stride = gridDim.x * 256;
    for (int i = idx; i < n8; i += stride) {
        const float4* s = (const float4*)src + (size_t)i * 2;
        float4 a = s[0], b = s[1];
        s16x8 o;
        o[0] = (short)f2bf(a.x); o[1] = (short)f2bf(a.y);
        o[2] = (short)f2bf(a.z); o[3] = (short)f2bf(a.w);
        o[4] = (short)f2bf(b.x); o[5] = (short)f2bf(b.y);
        o[6] = (short)f2bf(b.z); o[7] = (short)f2bf(b.w);
        *((s16x8*)dst + i) = o;
    }
}

// -------- transpose + convert: W[K][N] fp32 -> Wt[N][K] bf16 --------
__global__ __launch_bounds__(256) void k_transpose_bf16(
    const float* __restrict__ W, unsigned short* __restrict__ Wt, int K, int N) {
    __shared__ float t[64][65];
    const int nk = K >> 6;
    const int k0 = (blockIdx.x % nk) << 6;
    const int n0 = (blockIdx.x / nk) << 6;
    const int tid = threadIdx.x;
#pragma unroll
    for (int it = 0; it < 4; it++) {
        int idx = tid + (it << 8);
        int r = idx >> 4, c4 = (idx & 15) << 2;
        float4 v = *(const float4*)(W + (size_t)(k0 + r) * N + n0 + c4);
        t[r][c4] = v.x; t[r][c4 + 1] = v.y; t[r][c4 + 2] = v.z; t[r][c4 + 3] = v.w;
    }
    __syncthreads();
#pragma unroll
    for (int it = 0; it < 2; it++) {
        int idx = tid + (it << 8);
        int rn = idx >> 3, c8 = (idx & 7) << 3;
        s16x8 o;
#pragma unroll
        for (int j = 0; j < 8; j++) o[j] = (short)f2bf(t[c8 + j][rn]);
        *(s16x8*)(Wt + (size_t)(n0 + rn) * K + k0 + c8) = o;
    }
}

// ---------------- GEMM: C[M][N] = A[M][K] * Bt[N][K]^T ----------------
__global__ __launch_bounds__(256, 2) void k_gemm_bt(
    const unsigned short* __restrict__ A, const unsigned short* __restrict__ Bt,
    const float* __restrict__ bias, const float* __restrict__ wpe,
    unsigned short* __restrict__ Qo, unsigned short* __restrict__ Ko,
    unsigned short* __restrict__ Vo, float* __restrict__ Fo,
    int N, int K, int mode) {
    __shared__ unsigned short Alds[8192];   // [128][64] bf16, st-swizzled
    __shared__ unsigned short Blds[8192];
    const int tid = threadIdx.x;
    const int lane = tid & 63, wid = tid >> 6;
    const int ntile = N >> 7;
    const int m0 = (int)(blockIdx.x / ntile) << 7;
    const int n0 = (int)(blockIdx.x % ntile) << 7;
    const int wm = wid & 1, wn = wid >> 1;
    const int lr = lane >> 3, ls = lane & 7;
    const int l15 = lane & 15, lg = lane >> 4;

    const f32x4 vzero = {0.f, 0.f, 0.f, 0.f};
    f32x4 acc[4][4];
#pragma unroll
    for (int i = 0; i < 4; i++)
#pragma unroll
        for (int j = 0; j < 4; j++) acc[i][j] = vzero;

    for (int k0 = 0; k0 < K; k0 += 64) {
#pragma unroll
        for (int i = 0; i < 4; i++) {
            int r = (wid << 5) + (i << 3) + lr;
            int sl = (ls ^ (r & 7)) << 3;
            __builtin_amdgcn_global_load_lds(
                (const AS1 void*)(A + (size_t)(m0 + r) * K + k0 + sl),
                (AS3 void*)(Alds + (wid << 11) + (i << 9)), 16, 0, 0);
            __builtin_amdgcn_global_load_lds(
                (const AS1 void*)(Bt + (size_t)(n0 + r) * K + k0 + sl),
                (AS3 void*)(Blds + (wid << 11) + (i << 9)), 16, 0, 0);
        }
        __syncthreads();
#pragma unroll
        for (int kk = 0; kk < 2; kk++) {
            s16x8 af[4], bfr[4];
#pragma unroll
            for (int mi = 0; mi < 4; mi++) {
                int row = (wm << 6) + (mi << 4) + l15;
                int slot = lg + (kk << 2);
                af[mi] = *(const s16x8*)((const char*)Alds + row * 128 +
                                         ((slot ^ (row & 7)) << 4));
            }
#pragma unroll
            for (int ni = 0; ni < 4; ni++) {
                int row = (wn << 6) + (ni << 4) + l15;
                int slot = lg + (kk << 2);
                bfr[ni] = *(const s16x8*)((const char*)Blds + row * 128 +
                                          ((slot ^ (row & 7)) << 4));
            }
#pragma unroll
            for (int mi = 0; mi < 4; mi++)
#pragma unroll
                for (int ni = 0; ni < 4; ni++)
                    acc[mi][ni] = __builtin_amdgcn_mfma_f32_16x16x32_bf16(
                        af[mi], bfr[ni], acc[mi][ni], 0, 0, 0);
        }
        __syncthreads();
    }

    if (mode == 0) {
#pragma unroll
        for (int ni = 0; ni < 4; ni++) {
            int n = n0 + (wn << 6) + (ni << 4) + l15;
            int which = n >> 10, rem = n & 1023;
            int h = rem >> 6, s = rem & 63;
            unsigned short* out = (which == 0) ? Qo : ((which == 1) ? Ko : Vo);
            float bv = bias[n];
#pragma unroll
            for (int mi = 0; mi < 4; mi++) {
#pragma unroll
                for (int j = 0; j < 4; j++) {
                    int m = m0 + (wm << 6) + (mi << 4) + (lg << 2) + j;
                    int b = m >> 11, t = m & 2047;
                    float v = acc[mi][ni][j] + bv;
                    if (which < 2) v += wpe[((((t << 4) + h) & 2047) << 6) + s];
                    out[(size_t)(b * 16 + h) * 131072 + (size_t)t * 64 + s] = f2bf(v);
                }
            }
        }
    } else {
#pragma unroll
        for (int ni = 0; ni < 4; ni++) {
            int n = n0 + (wn << 6) + (ni << 4) + l15;
            float bv = bias[n];
#pragma unroll
            for (int mi = 0; mi < 4; mi++) {
#pragma unroll
                for (int j = 0; j < 4; j++) {
                    int m = m0 + (wm << 6) + (mi << 4) + (lg << 2) + j;
                    Fo[(size_t)m * N + n] = acc[mi][ni][j] + bv;
                }
            }
        }
    }
}

// ---------------- flash attention (causal), swapped-QK^T ----------------
// grid: 64 bh * 16 pairs; block handles q-tiles {pi, 31-pi} of 64 rows each
// (perfect causal balance: (pi+1)+(32-pi) = 33 kv-iters per block).
// 4 waves; wave owns 16 q-rows of the 64-row tile.
__global__ __launch_bounds__(256, 4) void k_attn(
    const unsigned short* __restrict__ Qg, const unsigned short* __restrict__ Kg,
    const unsigned short* __restrict__ Vg, unsigned short* __restrict__ Yg) {
    __shared__ unsigned short Klds[4096];    // [64 kv][64 s], swizzled (8KB)
    __shared__ unsigned short Vtlds[4096];   // [64 s][64 kv], swizzled (8KB)
    __shared__ unsigned short Plds[4096];    // per-wave [16 q][64 kv] (8KB)
    const int tid = threadIdx.x, lane = tid & 63, wid = tid >> 6;
    const int l15 = lane & 15, lg = lane >> 4;
    const int lr = lane >> 3, ls = lane & 7;
    const int bh = blockIdx.x >> 4, pi = blockIdx.x & 15;
    const int b = bh >> 4, h = bh & 15;
    const size_t base = (size_t)bh * 131072;
    // V staging mini-transpose mapping: thread covers kv4..+3 x d4..+3
    const int vkv4 = (tid >> 4) << 2;   // 0..60
    const int vd4 = (tid & 15) << 2;    // 0..60

    const f32x4 vzero = {0.f, 0.f, 0.f, 0.f};

#pragma unroll
    for (int phase = 0; phase < 2; phase++) {
        const int qtile = phase ? (31 - pi) : pi;
        const int q0 = qtile << 6;
        const int qrow = q0 + (wid << 4) + l15;

        s16x8 qf[2];
#pragma unroll
        for (int kk = 0; kk < 2; kk++)
            qf[kk] = *(const s16x8*)(Qg + base + (size_t)qrow * 64 +
                                     (kk << 5) + (lg << 3));

        f32x4 o[4];
#pragma unroll
        for (int i = 0; i < 4; i++) o[i] = vzero;
        float mrun = -3.0e38f, lrun = 0.f;

        const int nt = qtile + 1;
        for (int tI = 0; tI < nt; tI++) {
            const int kv0 = tI << 6;
            // stage K (async global->LDS, pre-swizzled source)
#pragma unroll
            for (int i = 0; i < 2; i++) {
                int r = (wid << 4) + (i << 3) + lr;
                int sl = (ls ^ (r & 7)) << 3;
                __builtin_amdgcn_global_load_lds(
                    (const AS1 void*)(Kg + base + (size_t)(kv0 + r) * 64 + sl),
                    (AS3 void*)(Klds + (wid << 10) + (i << 9)), 16, 0, 0);
            }
            // stage V transposed: 4x4 reg mini-transpose -> ds_write_b64
            {
                u16x4 vv[4];
#pragma unroll
                for (int r = 0; r < 4; r++)
                    vv[r] = *(const u16x4*)(Vg + base +
                                            (size_t)(kv0 + vkv4 + r) * 64 + vd4);
#pragma unroll
                for (int dj = 0; dj < 4; dj++) {
                    int row = vd4 + dj;
                    unsigned long long pk =
                        (unsigned long long)vv[0][dj] |
                        ((unsigned long long)vv[1][dj] << 16) |
                        ((unsigned long long)vv[2][dj] << 32) |
                        ((unsigned long long)vv[3][dj] << 48);
                    *(unsigned long long*)((char*)Vtlds + row * 128 +
                                           (((vkv4 >> 3) ^ (row & 7)) << 4) +
                                           ((vkv4 & 7) << 1)) = pk;
                }
            }
            __syncthreads();

            // S^T = K * Q^T  (acc: col=q=l15, row=kv=lg*4+j)
            f32x4 sacc[4];
#pragma unroll
            for (int i = 0; i < 4; i++) sacc[i] = vzero;
#pragma unroll
            for (int kk = 0; kk < 2; kk++) {
                s16x8 kf[4];
#pragma unroll
                for (int ki = 0; ki < 4; ki++) {
                    int row = (ki << 4) + l15;
                    int slot = lg + (kk << 2);
                    kf[ki] = *(const s16x8*)((const char*)Klds + row * 128 +
                                             ((slot ^ (row & 7)) << 4));
                }
#pragma unroll
                for (int ki = 0; ki < 4; ki++)
                    sacc[ki] = __builtin_amdgcn_mfma_f32_16x16x32_bf16(
                        kf[ki], qf[kk], sacc[ki], 0, 0, 0);
            }

            // online softmax (per q-column; in-lane 16 + 2 shfl_xor)
            float tm = -3.0e38f;
            if (tI == nt - 1) {   // diagonal tile: causal mask
#pragma unroll
                for (int ki = 0; ki < 4; ki++) {
#pragma unroll
                    for (int j = 0; j < 4; j++) {
                        int kvg = kv0 + (ki << 4) + (lg << 2) + j;
                        float sv = sacc[ki][j] * 0.125f;
                        if (kvg > qrow) sv = -3.0e38f;
                        sacc[ki][j] = sv;
                        tm = fmaxf(tm, sv);
                    }
                }
            } else {
#pragma unroll
                for (int ki = 0; ki < 4; ki++) {
#pragma unroll
                    for (int j = 0; j < 4; j++) {
                        float sv = sacc[ki][j] * 0.125f;
                        sacc[ki][j] = sv;
                        tm = fmaxf(tm, sv);
                    }
                }
            }
            tm = fmaxf(tm, __shfl_xor(tm, 16, 64));
            tm = fmaxf(tm, __shfl_xor(tm, 32, 64));
            float mnew = fmaxf(mrun, tm);
            float rfac = __expf(mrun - mnew);
            mrun = mnew;
            float ps = 0.f;
#pragma unroll
            for (int ki = 0; ki < 4; ki++) {
#pragma unroll
                for (int j = 0; j < 4; j++) {
                    float p = __expf(sacc[ki][j] - mnew);
                    sacc[ki][j] = p;
                    ps += p;
                }
            }
            ps += __shfl_xor(ps, 16, 64);
            ps += __shfl_xor(ps, 32, 64);
            lrun = lrun * rfac + ps;
            // rescale O (row q = lg*4+j needs column-q's factor)
#pragma unroll
            for (int j = 0; j < 4; j++) {
                float rj = __shfl(rfac, (lane & 48) | ((lg << 2) + j), 64);
#pragma unroll
                for (int si = 0; si < 4; si++) o[si][j] *= rj;
            }
            // pack P -> per-wave LDS (swizzled), b64 writes
#pragma unroll
            for (int ki = 0; ki < 4; ki++) {
                unsigned long long pk =
                    (unsigned long long)f2bf(sacc[ki][0]) |
                    ((unsigned long long)f2bf(sacc[ki][1]) << 16) |
                    ((unsigned long long)f2bf(sacc[ki][2]) << 32) |
                    ((unsigned long long)f2bf(sacc[ki][3]) << 48);
                int kvl = (ki << 4) + (lg << 2);
                int slot = kvl >> 3;
                *(unsigned long long*)((char*)Plds + (wid << 11) + l15 * 128 +
                                       ((slot ^ (l15 & 7)) << 4) +
                                       ((kvl & 7) << 1)) = pk;
            }

            // O += P * V
#pragma unroll
            for (int kk = 0; kk < 2; kk++) {
                s16x8 vf[4];
#pragma unroll
                for (int si = 0; si < 4; si++) {
                    int row = (si << 4) + l15;
                    int slot = lg + (kk << 2);
                    vf[si] = *(const s16x8*)((const char*)Vtlds + row * 128 +
                                             ((slot ^ (row & 7)) << 4));
                }
                int prow = l15;
                int slot = lg + (kk << 2);
                s16x8 pf = *(const s16x8*)((const char*)Plds + (wid << 11) +
                                           prow * 128 + ((slot ^ (prow & 7)) << 4));
#pragma unroll
                for (int si = 0; si < 4; si++)
                    o[si] = __builtin_amdgcn_mfma_f32_16x16x32_bf16(
                        pf, vf[si], o[si], 0, 0, 0);
            }
            __syncthreads();
        }

        // epilogue: divide by l, write y[b][t][h*64+s] bf16
#pragma unroll
        for (int j = 0; j < 4; j++) {
            float lv = __shfl(lrun, (lane & 48) | ((lg << 2) + j), 64);
            float linv = 1.0f / lv;
            int qg = q0 + (wid << 4) + (lg << 2) + j;
            size_t rowoff = ((size_t)b * 2048 + qg) * 1024 + (h << 6);
#pragma unroll
            for (int si = 0; si < 4; si++) {
                int sg = (si << 4) + l15;
                Yg[rowoff + sg] = f2bf(o[si][j] * linv);
            }
        }
    }
}

extern "C" void kernel_launch(void* const* d_in, const int* in_sizes, int n_in,
                              void* d_out, int out_size, void* d_ws, size_t ws_size,
                              hipStream_t stream) {
    const float* x   = (const float*)d_in[0];
    const float* w1  = (const float*)d_in[1];
    const float* b1  = (const float*)d_in[2];
    const float* w2  = (const float*)d_in[3];
    const float* b2  = (const float*)d_in[4];
    const float* wpe = (const float*)d_in[5];
    float* out = (float*)d_out;

    char* ws = (char*)d_ws;
    unsigned short* xb  = (unsigned short*)(ws);              // 16.78 MB
    unsigned short* w1t = (unsigned short*)(ws + 16777216);   //  6.29 MB
    unsigned short* w2t = (unsigned short*)(ws + 23068672);   //  2.10 MB
    unsigned short* Qb  = (unsigned short*)(ws + 25165824);   // 16.78 MB
    unsigned short* Kb  = (unsigned short*)(ws + 41943040);   // 16.78 MB
    unsigned short* Vb  = (unsigned short*)(ws + 58720256);   // 16.78 MB
    unsigned short* Yb  = (unsigned short*)(ws + 75497472);   // 16.78 MB -> 92.3 MB total

    k_f32_to_bf16<<<2048, 256, 0, stream>>>(x, xb, 8388608 / 8);
    k_transpose_bf16<<<768, 256, 0, stream>>>(w1, w1t, 1024, 3072);
    k_transpose_bf16<<<256, 256, 0, stream>>>(w2, w2t, 1024, 1024);
    k_gemm_bt<<<64 * 24, 256, 0, stream>>>(xb, w1t, b1, wpe, Qb, Kb, Vb,
                                           nullptr, 3072, 1024, 0);
    k_attn<<<1024, 256, 0, stream>>>(Qb, Kb, Vb, Yb);
    k_gemm_bt<<<64 * 8, 256, 0, stream>>>(Yb, w2t, b2, nullptr, nullptr, nullptr,
                                          nullptr, out, 1024, 1024, 1);
}

// Round 3
// 302.594 us; speedup vs baseline: 1.2682x; 1.0330x over previous
//
#include <hip/hip_runtime.h>

typedef __attribute__((ext_vector_type(8))) short s16x8;
typedef __attribute__((ext_vector_type(4))) float f32x4;
typedef __attribute__((ext_vector_type(4))) unsigned short u16x4;

#define AS1 __attribute__((address_space(1)))
#define AS3 __attribute__((address_space(3)))

__device__ __forceinline__ unsigned short f2bf(float f) {
    union { float f; unsigned u; } c; c.f = f;
    return (unsigned short)((c.u + 0x7FFFu + ((c.u >> 16) & 1u)) >> 16);
}

// ---------------- fp32 -> bf16 convert (vectorized) ----------------
__global__ void k_f32_to_bf16(const float* __restrict__ src,
                              unsigned short* __restrict__ dst, int n8) {
    int idx = blockIdx.x * 256 + threadIdx.x;
    int stride = gridDim.x * 256;
    for (int i = idx; i < n8; i += stride) {
        const float4* s = (const float4*)src + (size_t)i * 2;
        float4 a = s[0], b = s[1];
        s16x8 o;
        o[0] = (short)f2bf(a.x); o[1] = (short)f2bf(a.y);
        o[2] = (short)f2bf(a.z); o[3] = (short)f2bf(a.w);
        o[4] = (short)f2bf(b.x); o[5] = (short)f2bf(b.y);
        o[6] = (short)f2bf(b.z); o[7] = (short)f2bf(b.w);
        *((s16x8*)dst + i) = o;
    }
}

// -------- transpose + convert: W[K][N] fp32 -> Wt[N][K] bf16 --------
__global__ __launch_bounds__(256) void k_transpose_bf16(
    const float* __restrict__ W, unsigned short* __restrict__ Wt, int K, int N) {
    __shared__ float t[64][65];
    const int nk = K >> 6;
    const int k0 = (blockIdx.x % nk) << 6;
    const int n0 = (blockIdx.x / nk) << 6;
    const int tid = threadIdx.x;
#pragma unroll
    for (int it = 0; it < 4; it++) {
        int idx = tid + (it << 8);
        int r = idx >> 4, c4 = (idx & 15) << 2;
        float4 v = *(const float4*)(W + (size_t)(k0 + r) * N + n0 + c4);
        t[r][c4] = v.x; t[r][c4 + 1] = v.y; t[r][c4 + 2] = v.z; t[r][c4 + 3] = v.w;
    }
    __syncthreads();
#pragma unroll
    for (int it = 0; it < 2; it++) {
        int idx = tid + (it << 8);
        int rn = idx >> 3, c8 = (idx & 7) << 3;
        s16x8 o;
#pragma unroll
        for (int j = 0; j < 8; j++) o[j] = (short)f2bf(t[c8 + j][rn]);
        *(s16x8*)(Wt + (size_t)(n0 + rn) * K + k0 + c8) = o;
    }
}

// ---------------- GEMM: C[M][N] = A[M][K] * Bt[N][K]^T ----------------
__global__ __launch_bounds__(256, 2) void k_gemm_bt(
    const unsigned short* __restrict__ A, const unsigned short* __restrict__ Bt,
    const float* __restrict__ bias, const float* __restrict__ wpe,
    unsigned short* __restrict__ Qo, unsigned short* __restrict__ Ko,
    unsigned short* __restrict__ Vo, float* __restrict__ Fo,
    int N, int K, int mode) {
    __shared__ unsigned short Alds[8192];   // [128][64] bf16, st-swizzled
    __shared__ unsigned short Blds[8192];
    const int tid = threadIdx.x;
    const int lane = tid & 63, wid = tid >> 6;
    const int ntile = N >> 7;
    // bijective XCD-chunked remap (T1): all blocks of one m-panel chunk on one XCD
    const int chunk = (int)gridDim.x >> 3;
    const int l = ((int)blockIdx.x & 7) * chunk + ((int)blockIdx.x >> 3);
    const int m0 = (l / ntile) << 7;
    const int n0 = (l % ntile) << 7;
    const int wm = wid & 1, wn = wid >> 1;
    const int lr = lane >> 3, ls = lane & 7;
    const int l15 = lane & 15, lg = lane >> 4;

    const f32x4 vzero = {0.f, 0.f, 0.f, 0.f};
    f32x4 acc[4][4];
#pragma unroll
    for (int i = 0; i < 4; i++)
#pragma unroll
        for (int j = 0; j < 4; j++) acc[i][j] = vzero;

    for (int k0 = 0; k0 < K; k0 += 64) {
#pragma unroll
        for (int i = 0; i < 4; i++) {
            int r = (wid << 5) + (i << 3) + lr;
            int sl = (ls ^ (r & 7)) << 3;
            __builtin_amdgcn_global_load_lds(
                (const AS1 void*)(A + (size_t)(m0 + r) * K + k0 + sl),
                (AS3 void*)(Alds + (wid << 11) + (i << 9)), 16, 0, 0);
            __builtin_amdgcn_global_load_lds(
                (const AS1 void*)(Bt + (size_t)(n0 + r) * K + k0 + sl),
                (AS3 void*)(Blds + (wid << 11) + (i << 9)), 16, 0, 0);
        }
        __syncthreads();
#pragma unroll
        for (int kk = 0; kk < 2; kk++) {
            s16x8 af[4], bfr[4];
#pragma unroll
            for (int mi = 0; mi < 4; mi++) {
                int row = (wm << 6) + (mi << 4) + l15;
                int slot = lg + (kk << 2);
                af[mi] = *(const s16x8*)((const char*)Alds + row * 128 +
                                         ((slot ^ (row & 7)) << 4));
            }
#pragma unroll
            for (int ni = 0; ni < 4; ni++) {
                int row = (wn << 6) + (ni << 4) + l15;
                int slot = lg + (kk << 2);
                bfr[ni] = *(const s16x8*)((const char*)Blds + row * 128 +
                                          ((slot ^ (row & 7)) << 4));
            }
#pragma unroll
            for (int mi = 0; mi < 4; mi++)
#pragma unroll
                for (int ni = 0; ni < 4; ni++)
                    acc[mi][ni] = __builtin_amdgcn_mfma_f32_16x16x32_bf16(
                        af[mi], bfr[ni], acc[mi][ni], 0, 0, 0);
        }
        __syncthreads();
    }

    if (mode == 0) {
#pragma unroll
        for (int ni = 0; ni < 4; ni++) {
            int n = n0 + (wn << 6) + (ni << 4) + l15;
            int which = n >> 10, rem = n & 1023;
            int h = rem >> 6, s = rem & 63;
            unsigned short* out = (which == 0) ? Qo : ((which == 1) ? Ko : Vo);
            float bv = bias[n];
#pragma unroll
            for (int mi = 0; mi < 4; mi++) {
#pragma unroll
                for (int j = 0; j < 4; j++) {
                    int m = m0 + (wm << 6) + (mi << 4) + (lg << 2) + j;
                    int b = m >> 11, t = m & 2047;
                    float v = acc[mi][ni][j] + bv;
                    if (which < 2) v += wpe[((((t << 4) + h) & 2047) << 6) + s];
                    out[(size_t)(b * 16 + h) * 131072 + (size_t)t * 64 + s] = f2bf(v);
                }
            }
        }
    } else {
#pragma unroll
        for (int ni = 0; ni < 4; ni++) {
            int n = n0 + (wn << 6) + (ni << 4) + l15;
            float bv = bias[n];
#pragma unroll
            for (int mi = 0; mi < 4; mi++) {
#pragma unroll
                for (int j = 0; j < 4; j++) {
                    int m = m0 + (wm << 6) + (mi << 4) + (lg << 2) + j;
                    Fo[(size_t)m * N + n] = acc[mi][ni][j] + bv;
                }
            }
        }
    }
}

// ---------------- flash attention (causal), swapped-QK^T ----------------
// grid: 2048 blocks = 64 bh x 32 q-tiles (64 rows). Mapping: xcd=bid&7 so all
// 32 blocks of a bh land on one XCD (K/V 512KB x 8 bh = 4MB ~ L2); qt-major
// DESCENDING so the longest blocks start first. 6 blocks/CU (LDS 24KB).
__global__ __launch_bounds__(256, 6) void k_attn(
    const unsigned short* __restrict__ Qg, const unsigned short* __restrict__ Kg,
    const unsigned short* __restrict__ Vg, unsigned short* __restrict__ Yg) {
    __shared__ unsigned short Klds[4096];    // [64 kv][64 s], swizzled (8KB)
    __shared__ unsigned short Vtlds[4096];   // [64 s][64 kv], fv-swizzled (8KB)
    __shared__ unsigned short Plds[4096];    // per-wave [16 q][64 kv] (8KB)
    const int tid = threadIdx.x, lane = tid & 63, wid = tid >> 6;
    const int l15 = lane & 15, lg = lane >> 4;
    const int lr = lane >> 3, ls = lane & 7;
    const int p = blockIdx.x;
    const int xcd = p & 7, rank = p >> 3;
    const int qt = 31 - (rank >> 3);          // descending work
    const int bh = ((rank & 7) << 3) | xcd;   // bh colocated on xcd
    const int b = bh >> 4, h = bh & 15;
    const size_t base = (size_t)bh * 131072;
    const int q0 = qt << 6;
    const int qrow = q0 + (wid << 4) + l15;
    const int vkv4 = (tid >> 4) << 2;   // 0..60
    const int vd4 = (tid & 15) << 2;    // 0..60

    const f32x4 vzero = {0.f, 0.f, 0.f, 0.f};

    s16x8 qf[2];
#pragma unroll
    for (int kk = 0; kk < 2; kk++)
        qf[kk] = *(const s16x8*)(Qg + base + (size_t)qrow * 64 +
                                 (kk << 5) + (lg << 3));

    f32x4 o[4];
#pragma unroll
    for (int i = 0; i < 4; i++) o[i] = vzero;
    float mrun = -3.0e38f, lrun = 0.f;   // mrun in RAW score domain

    const int nt = qt + 1;
    for (int tI = 0; tI < nt; tI++) {
        const int kv0 = tI << 6;
        // stage K (async global->LDS, pre-swizzled source)
#pragma unroll
        for (int i = 0; i < 2; i++) {
            int r = (wid << 4) + (i << 3) + lr;
            int sl = (ls ^ (r & 7)) << 3;
            __builtin_amdgcn_global_load_lds(
                (const AS1 void*)(Kg + base + (size_t)(kv0 + r) * 64 + sl),
                (AS3 void*)(Klds + (wid << 10) + (i << 9)), 16, 0, 0);
        }
        // stage V transposed: 4x4 reg mini-transpose -> ds_write_b64
        // fv(row) spreads the 16 writes of a lane-group across banks (4-way floor)
        {
            u16x4 vv[4];
#pragma unroll
            for (int r = 0; r < 4; r++)
                vv[r] = *(const u16x4*)(Vg + base +
                                        (size_t)(kv0 + vkv4 + r) * 64 + vd4);
#pragma unroll
            for (int dj = 0; dj < 4; dj++) {
                int row = vd4 + dj;
                int fv = (row ^ (row >> 3)) & 7;
                unsigned long long pk =
                    (unsigned long long)vv[0][dj] |
                    ((unsigned long long)vv[1][dj] << 16) |
                    ((unsigned long long)vv[2][dj] << 32) |
                    ((unsigned long long)vv[3][dj] << 48);
                *(unsigned long long*)((char*)Vtlds + row * 128 +
                                       ((((vkv4 >> 3) ^ fv) & 7) << 4) +
                                       ((vkv4 & 7) << 1)) = pk;
            }
        }
        __syncthreads();

        // S^T = K * Q^T  (acc: col=q=l15, row=kv=lg*4+j)
        f32x4 sacc[4];
#pragma unroll
        for (int i = 0; i < 4; i++) sacc[i] = vzero;
        __builtin_amdgcn_s_setprio(1);
#pragma unroll
        for (int kk = 0; kk < 2; kk++) {
            s16x8 kf[4];
#pragma unroll
            for (int ki = 0; ki < 4; ki++) {
                int row = (ki << 4) + l15;
                int slot = lg + (kk << 2);
                kf[ki] = *(const s16x8*)((const char*)Klds + row * 128 +
                                         ((slot ^ (row & 7)) << 4));
            }
#pragma unroll
            for (int ki = 0; ki < 4; ki++)
                sacc[ki] = __builtin_amdgcn_mfma_f32_16x16x32_bf16(
                    kf[ki], qf[kk], sacc[ki], 0, 0, 0);
        }
        __builtin_amdgcn_s_setprio(0);

        // online softmax in raw-score domain (scale folded into exp arg)
        float tm = -3.0e38f;
        if (tI == nt - 1) {   // diagonal tile: causal mask
#pragma unroll
            for (int ki = 0; ki < 4; ki++) {
#pragma unroll
                for (int j = 0; j < 4; j++) {
                    int kvg = kv0 + (ki << 4) + (lg << 2) + j;
                    float sv = sacc[ki][j];
                    if (kvg > qrow) sv = -3.0e38f;
                    sacc[ki][j] = sv;
                    tm = fmaxf(tm, sv);
                }
            }
        } else {
#pragma unroll
            for (int ki = 0; ki < 4; ki++) {
#pragma unroll
                for (int j = 0; j < 4; j++) tm = fmaxf(tm, sacc[ki][j]);
            }
        }
        tm = fmaxf(tm, __shfl_xor(tm, 16, 64));
        tm = fmaxf(tm, __shfl_xor(tm, 32, 64));
        float mnew = fmaxf(mrun, tm);
        float rfac = __expf((mrun - mnew) * 0.125f);
        float m8 = mnew * 0.125f;
        mrun = mnew;
        float ps = 0.f;
#pragma unroll
        for (int ki = 0; ki < 4; ki++) {
#pragma unroll
            for (int j = 0; j < 4; j++) {
                float pv = __expf(__builtin_fmaf(sacc[ki][j], 0.125f, -m8));
                sacc[ki][j] = pv;
                ps += pv;
            }
        }
        ps += __shfl_xor(ps, 16, 64);
        ps += __shfl_xor(ps, 32, 64);
        lrun = lrun * rfac + ps;
        // rescale O (row q = lg*4+j needs column-q's factor)
#pragma unroll
        for (int j = 0; j < 4; j++) {
            float rj = __shfl(rfac, (lane & 48) | ((lg << 2) + j), 64);
#pragma unroll
            for (int si = 0; si < 4; si++) o[si][j] *= rj;
        }
        // pack P -> per-wave LDS (swizzled), b64 writes
#pragma unroll
        for (int ki = 0; ki < 4; ki++) {
            unsigned long long pk =
                (unsigned long long)f2bf(sacc[ki][0]) |
                ((unsigned long long)f2bf(sacc[ki][1]) << 16) |
                ((unsigned long long)f2bf(sacc[ki][2]) << 32) |
                ((unsigned long long)f2bf(sacc[ki][3]) << 48);
            int kvl = (ki << 4) + (lg << 2);
            int slot = kvl >> 3;
            *(unsigned long long*)((char*)Plds + (wid << 11) + l15 * 128 +
                                   ((slot ^ (l15 & 7)) << 4) +
                                   ((kvl & 7) << 1)) = pk;
        }

        // O += P * V
        __builtin_amdgcn_s_setprio(1);
#pragma unroll
        for (int kk = 0; kk < 2; kk++) {
            s16x8 vf[4];
#pragma unroll
            for (int si = 0; si < 4; si++) {
                int row = (si << 4) + l15;
                int slot = lg + (kk << 2);
                int fv = (row ^ (row >> 3)) & 7;
                vf[si] = *(const s16x8*)((const char*)Vtlds + row * 128 +
                                         (((slot ^ fv) & 7) << 4));
            }
            int prow = l15;
            int slot = lg + (kk << 2);
            s16x8 pf = *(const s16x8*)((const char*)Plds + (wid << 11) +
                                       prow * 128 + ((slot ^ (prow & 7)) << 4));
#pragma unroll
            for (int si = 0; si < 4; si++)
                o[si] = __builtin_amdgcn_mfma_f32_16x16x32_bf16(
                    pf, vf[si], o[si], 0, 0, 0);
        }
        __builtin_amdgcn_s_setprio(0);
        __syncthreads();
    }

    // epilogue: divide by l, write y[b][t][h*64+s] bf16
#pragma unroll
    for (int j = 0; j < 4; j++) {
        float lv = __shfl(lrun, (lane & 48) | ((lg << 2) + j), 64);
        float linv = 1.0f / lv;
        int qg = q0 + (wid << 4) + (lg << 2) + j;
        size_t rowoff = ((size_t)b * 2048 + qg) * 1024 + (h << 6);
#pragma unroll
        for (int si = 0; si < 4; si++) {
            int sg = (si << 4) + l15;
            Yg[rowoff + sg] = f2bf(o[si][j] * linv);
        }
    }
}

extern "C" void kernel_launch(void* const* d_in, const int* in_sizes, int n_in,
                              void* d_out, int out_size, void* d_ws, size_t ws_size,
                              hipStream_t stream) {
    const float* x   = (const float*)d_in[0];
    const float* w1  = (const float*)d_in[1];
    const float* b1  = (const float*)d_in[2];
    const float* w2  = (const float*)d_in[3];
    const float* b2  = (const float*)d_in[4];
    const float* wpe = (const float*)d_in[5];
    float* out = (float*)d_out;

    char* ws = (char*)d_ws;
    unsigned short* xb  = (unsigned short*)(ws);              // 16.78 MB
    unsigned short* w1t = (unsigned short*)(ws + 16777216);   //  6.29 MB
    unsigned short* w2t = (unsigned short*)(ws + 23068672);   //  2.10 MB
    unsigned short* Qb  = (unsigned short*)(ws + 25165824);   // 16.78 MB
    unsigned short* Kb  = (unsigned short*)(ws + 41943040);   // 16.78 MB
    unsigned short* Vb  = (unsigned short*)(ws + 58720256);   // 16.78 MB
    unsigned short* Yb  = (unsigned short*)(ws + 75497472);   // 16.78 MB -> 92.3 MB total

    k_f32_to_bf16<<<2048, 256, 0, stream>>>(x, xb, 8388608 / 8);
    k_transpose_bf16<<<768, 256, 0, stream>>>(w1, w1t, 1024, 3072);
    k_transpose_bf16<<<256, 256, 0, stream>>>(w2, w2t, 1024, 1024);
    k_gemm_bt<<<64 * 24, 256, 0, stream>>>(xb, w1t, b1, wpe, Qb, Kb, Vb,
                                           nullptr, 3072, 1024, 0);
    k_attn<<<2048, 256, 0, stream>>>(Qb, Kb, Vb, Yb);
    k_gemm_bt<<<64 * 8, 256, 0, stream>>>(Yb, w2t, b2, nullptr, nullptr, nullptr,
                                          nullptr, out, 1024, 1024, 1);
}